// Round 2
// baseline (357.141 us; speedup 1.0000x reference)
//
#include <hip/hip_runtime.h>
#include <cstdint>
#include <cstddef>

// ---------------- workspace layout ----------------
// xp  : [32][58][58][256] bf16  (NHWC, spatial halo of zeros)  = 55,115,776 B
// Wb  : [256][2304] bf16 (sign(w) as +-1; k = tap*256 + c)     =  1,179,648 B
// alpha: [256] f32
#define WB_OFF   55115776ull
#define AL_OFF   (WB_OFF + 1179648ull)

typedef __bf16 bf16x8 __attribute__((ext_vector_type(8)));
typedef float  f32x4  __attribute__((ext_vector_type(4)));

static __device__ __forceinline__ unsigned short f2bf(float f) {
  union { float f; unsigned int u; } v; v.f = f;
  unsigned int u = v.u;
  u += 0x7FFFu + ((u >> 16) & 1u);   // RNE
  return (unsigned short)(u >> 16);
}

static __device__ __forceinline__ void async16(void* lds, const void* g) {
  __builtin_amdgcn_global_load_lds(
      (const __attribute__((address_space(1))) unsigned int*)g,
      (__attribute__((address_space(3))) unsigned int*)lds, 16, 0, 0);
}

// ---------------- weight prep: alpha[o] + sign(w) in bf16, k = tap*256+c ----
__global__ void prep_w(const float* __restrict__ w, unsigned short* __restrict__ wb,
                       float* __restrict__ alpha) {
  const int o = blockIdx.x, c = threadIdx.x;
  const float* wr = w + (size_t)(o * 256 + c) * 9;
  float s = 0.f;
#pragma unroll
  for (int tap = 0; tap < 9; ++tap) {
    float v = wr[tap];
    s += fabsf(v);
    unsigned short sg = (v > 0.f) ? 0x3F80u : ((v < 0.f) ? 0xBF80u : 0u);
    wb[(size_t)o * 2304 + tap * 256 + c] = sg;
  }
  __shared__ float red[256];
  red[c] = s;
  __syncthreads();
  for (int d = 128; d > 0; d >>= 1) {
    if (c < d) red[c] += red[c + d];
    __syncthreads();
  }
  if (c == 0) alpha[o] = red[0] * (1.f / 2304.f);
}

// ---------------- x prep: NCHW f32 -> NHWC bf16 with halo (LDS transpose) ----
// grid = 32*58 blocks (one per (n, padded-row)), 256 threads.
__global__ __launch_bounds__(256) void prep_x(const float* __restrict__ x,
                                              unsigned short* __restrict__ xp) {
  const int bx = blockIdx.x;
  const int n = bx / 58, hp = bx % 58;
  const int t = threadIdx.x;
  unsigned short* row = xp + (size_t)(n * 58 + hp) * 58 * 256;

  if (hp == 0 || hp == 57) {            // halo rows: all zero
    uint32_t* r32 = (uint32_t*)row;
    for (int i = t; i < 7424; i += 256) r32[i] = 0;
    return;
  }
  const int h = hp - 1;
  __shared__ unsigned short tile[56 * 258];   // [w][c], stride 258 -> bank stride 1

  const int w = t & 63, cw = t >> 6;          // 4 channel rows per iteration
  if (w < 56) {
    const float* src = x + ((size_t)(n * 256 + cw) * 56 + h) * 56 + w;
#pragma unroll 8
    for (int k = 0; k < 64; ++k) {
      tile[w * 258 + (k * 4 + cw)] = f2bf(*src);
      src += (size_t)4 * 3136;               // c += 4
    }
  }
  __syncthreads();

  uint32_t* r32 = (uint32_t*)row;
  if (t < 128) { r32[t] = 0; r32[57 * 128 + t] = 0; }  // halo columns w'=0,57
#pragma unroll
  for (int it = 0; it < 28; ++it) {
    const int id = it * 256 + t;
    const int ww = id >> 7, cp = id & 127;
    const uint32_t lo = tile[ww * 258 + 2 * cp];
    const uint32_t hi = tile[ww * 258 + 2 * cp + 1];
    r32[(ww + 1) * 128 + cp] = lo | (hi << 16);
  }
}

// ---------------- implicit-GEMM conv: C[o][pix] = Wb * Xp ----------------
// M=256 (2 tiles of 128), N=100352 (784 tiles of 128), K=2304: 9 taps x 4 cc of 64
// LDS rows are 128 B (8 chunks of 16 B), XOR-swizzled: chunk c of row r lives at
// position c ^ (r&7). global_load_lds writes lane-linear; we permute the SOURCE.
__global__ __launch_bounds__(256, 4)
void conv_mfma(const unsigned short* __restrict__ xp,
               const unsigned short* __restrict__ wb,
               const float* __restrict__ alpha,
               float* __restrict__ out) {
  __shared__ __align__(16) char lds[32768];
  char* ldsA = lds;            // 128 rows (o)   x 128 B
  char* ldsB = lds + 16384;    // 128 rows (pix) x 128 B

  const int tid = threadIdx.x;
  const int wave = tid >> 6, lane = tid & 63;
  const int wm = wave >> 1, wn = wave & 1;
  const int o0 = (blockIdx.x >= 784) ? 128 : 0;      // pair (b, b+784) shares B-tile,
  const int pix0 = (blockIdx.x % 784) * 128;         // 784%8==0 -> same XCD

  const int rsub = lane >> 3;                 // row within 8-row group
  const int schunk = (lane & 7) ^ rsub;       // swizzled source chunk

  const char* gA[4];
  const char* gB[4];
#pragma unroll
  for (int j = 0; j < 4; ++j) {
    const int row = (wave * 4 + j) * 8 + rsub;          // 0..127
    gA[j] = (const char*)wb + (size_t)(o0 + row) * 4608 + schunk * 16;
    const int pix = pix0 + row;
    const int n = pix / 3136, rem = pix % 3136;
    const int h = rem / 56, ww = rem % 56;
    gB[j] = (const char*)xp + (size_t)((n * 58 + h) * 58 + ww) * 512 + schunk * 16;
  }

  f32x4 acc[4][4];
#pragma unroll
  for (int i = 0; i < 4; ++i)
#pragma unroll
    for (int j = 0; j < 4; ++j) acc[i][j] = (f32x4){0.f, 0.f, 0.f, 0.f};

  const int ar = lane & 15, aq = lane >> 4;
  const int sw = ar & 7;                      // frag-read swizzle key (r&7 == ar&7)

  for (int tap = 0; tap < 9; ++tap) {
    const int tapoff = ((tap / 3) * 58 + (tap % 3)) * 512;
#pragma unroll
    for (int cc = 0; cc < 4; ++cc) {
      const int kA = tap * 512 + cc * 128;    // byte offset into Wb row
      const int kB = tapoff + cc * 128;       // byte offset into xp
      __syncthreads();                        // prev-iter frag reads done
#pragma unroll
      for (int j = 0; j < 4; ++j) {
        async16(ldsA + (wave * 4 + j) * 1024, gA[j] + kA);
        async16(ldsB + (wave * 4 + j) * 1024, gB[j] + kB);
      }
      __syncthreads();                        // vmcnt(0) drained here
#pragma unroll
      for (int kk = 0; kk < 2; ++kk) {
        bf16x8 af[4], bfr[4];
#pragma unroll
        for (int mi = 0; mi < 4; ++mi)
          af[mi] = *(const bf16x8*)(ldsA + (wm * 64 + mi * 16 + ar) * 128 +
                                    (((kk * 4 + aq) ^ sw) * 16));
#pragma unroll
        for (int ni = 0; ni < 4; ++ni)
          bfr[ni] = *(const bf16x8*)(ldsB + (wn * 64 + ni * 16 + ar) * 128 +
                                     (((kk * 4 + aq) ^ sw) * 16));
#pragma unroll
        for (int mi = 0; mi < 4; ++mi)
#pragma unroll
          for (int ni = 0; ni < 4; ++ni)
            acc[mi][ni] = __builtin_amdgcn_mfma_f32_16x16x32_bf16(af[mi], bfr[ni],
                                                                  acc[mi][ni], 0, 0, 0);
      }
    }
  }

  // epilogue: D[row=o][col=pix], col=lane&15, row=(lane>>4)*4+r ; scale by alpha[o]
  int nc[4], rc[4];
#pragma unroll
  for (int ni = 0; ni < 4; ++ni) {
    const int pix = pix0 + wn * 64 + ni * 16 + ar;
    nc[ni] = pix / 3136; rc[ni] = pix % 3136;
  }
#pragma unroll
  for (int mi = 0; mi < 4; ++mi) {
    const int orow = o0 + wm * 64 + mi * 16 + aq * 4;
    float al[4];
#pragma unroll
    for (int r = 0; r < 4; ++r) al[r] = alpha[orow + r];
#pragma unroll
    for (int ni = 0; ni < 4; ++ni) {
      const size_t base = (size_t)nc[ni] * 802816 + (size_t)orow * 3136 + (size_t)rc[ni];
#pragma unroll
      for (int r = 0; r < 4; ++r)
        out[base + (size_t)r * 3136] = acc[mi][ni][r] * al[r];
    }
  }
}

extern "C" void kernel_launch(void* const* d_in, const int* in_sizes, int n_in,
                              void* d_out, int out_size, void* d_ws, size_t ws_size,
                              hipStream_t stream) {
  const float* x = (const float*)d_in[0];
  const float* w = (const float*)d_in[1];
  char* ws = (char*)d_ws;
  unsigned short* xp  = (unsigned short*)ws;
  unsigned short* wbp = (unsigned short*)(ws + WB_OFF);
  float* alpha = (float*)(ws + AL_OFF);
  float* out = (float*)d_out;

  prep_w<<<256, 256, 0, stream>>>(w, wbp, alpha);
  prep_x<<<32 * 58, 256, 0, stream>>>(x, xp);
  conv_mfma<<<1568, 256, 0, stream>>>(xp, wbp, alpha, out);
}